// Round 5
// baseline (363.089 us; speedup 1.0000x reference)
//
#include <hip/hip_runtime.h>
#include <stdint.h>

// GRU encoder B=512,T=512,H=256,IN=2 — R13: serial-chain micro-squeeze on R12.
// R12 base: i8 MFMA K=64 (48 MFMA/SIMD/step ~980 cyc pipe floor), h quantized
// scale 127, W scale 2032, gates f32, hp unquantized in reg. absmax 0.00195.
// R13 changes (attack the ~525-cyc serial remainder):
//  1. exp2-folded sigmoid/tanh: the 1.4427 / 2.8854 exp scales AND the INVS
//     dequant scale are folded into pre-scaled loop-invariant constants.
//     r-chain and z-tail each lose 2 VALU ops; tanh loses 2.
//  2. No per-step output store: freeze keeps hp correct; single *op = hp
//     after the loop (-cmp -store per step).
//  3. Phase B reuses phase-A A-frag registers (no LDS re-read; loads remain
//     inline next to first use — R10 style, not R11's failed pre-burst).
//  4. (hp-n) precomputed under phase B; true tail = z -> fma -> quant -> write.
// Floor re-derivation: per-SIMD MFMA/step = 192/4 = 48 for ANY batches/block
// (redundancy cancels; CU-limited); cross-block split needs per-step grid
// sync; wall = max-length block ~512 steps. 980-cyc floor structural.

typedef int   v4i   __attribute__((ext_vector_type(4)));

#define BB 512
#define TT 512
#define HH 256
#define NCT 48     // 768/16 col tiles
#define KTI 4      // 256/64 k tiles (i8)
#define HSTR8 320  // padded h8 byte stride per batch
#define WSCALE 2032.0f
#define INVS (1.0f/(2032.0f*127.0f))
#define L2E  1.44269504f       // log2(e)
#define T2E  2.88539008f       // 2*log2(e)

// Wp[(ct*KTI + kt)*64 + lane] = 16 bytes W_hh[16ct + (lane&15)][64kt + (lane>>4)*16 + j]
__global__ void prep_pack_i8(const float* __restrict__ Whh, uint4* __restrict__ Wp) {
    int n = blockIdx.x * blockDim.x + threadIdx.x;   // [0, 48*4*64 = 12288)
    int lane = n & 63;
    int kt = (n >> 6) & (KTI - 1);
    int ct = n >> 8;
    int row = 16 * ct + (lane & 15);
    int k0  = 64 * kt + (lane >> 4) * 16;
    const float* src = Whh + (size_t)row * HH + k0;
    uint dw[4];
    #pragma unroll
    for (int d = 0; d < 4; ++d) {
        uint acc = 0;
        #pragma unroll
        for (int j = 0; j < 4; ++j) {
            int q = (int)rintf(src[4 * d + j] * WSCALE);
            q = q < -127 ? -127 : (q > 127 ? 127 : q);
            acc |= ((uint)(q & 0xff)) << (8 * j);
        }
        dw[d] = acc;
    }
    Wp[n] = uint4{dw[0], dw[1], dw[2], dw[3]};
}

__global__ void __launch_bounds__(512, 1)
gru_persist(const float* __restrict__ x,        // [B,T,2]
            const int* __restrict__ len,        // [B]
            const float* __restrict__ h0,       // [B,H]
            const float* __restrict__ Wih,      // [768,2]
            const float* __restrict__ bih,      // [768]
            const float* __restrict__ bhh,      // [768]
            const uint4* __restrict__ Wp,       // i8-packed W_hh fragments
            float* __restrict__ out)            // [B,H]
{
    __shared__ __align__(16) int8_t h8[2][2][HSTR8];   // [buf][batch][e]

    const int tid  = threadIdx.x;
    const int lane = tid & 63;
    const int w    = tid >> 6;          // wave 0..7
    const int b0   = blockIdx.x * 2;

    // ---- W B-fragments for this wave's 6 tiles: 96 dwords in regs ----
    v4i wfr[6][KTI];
    {
        const int cts[6] = {2*w, 2*w+1, 16+2*w, 16+2*w+1, 32+2*w, 32+2*w+1};
        #pragma unroll
        for (int c = 0; c < 6; ++c)
            #pragma unroll
            for (int kt = 0; kt < KTI; ++kt)
                wfr[c][kt] = __builtin_bit_cast(v4i, Wp[(cts[c] * KTI + kt) * 64 + lane]);
    }
    #pragma unroll
    for (int c = 0; c < 6; ++c)
        #pragma unroll
        for (int kt = 0; kt < KTI; ++kt)
            asm volatile("" : "+v"(wfr[c][kt]));   // reg-resident, not remat

    // ---- gate-slot mapping: one slot per lane ----
    const int batch = (lane >> 4) & 1;
    const int e = 32 * w + (lane & 15) + ((lane >> 5) << 4);

    // ---- loop-invariant gate constants, PRE-SCALED for exp2 folding ----
    // sigmoid(x) = rcp(1 + exp2(-L2E*x))  -> r/z inputs pre-multiplied -L2E
    // tanh(y): e = exp2(-T2E*y)           -> n input pre-multiplied -T2E
    const float ccxs = -L2E * (bih[e] + bhh[e]);                 // r bias'
    const float ccys = -L2E * (bih[HH + e] + bhh[HH + e]);       // z bias'
    const float cczs = -T2E * bih[2 * HH + e];                   // n input bias'
    const float ccw2 = -T2E * bhh[2 * HH + e];                   // n hidden bias'
    const float wxr0 = -L2E * Wih[2 * e],            wxr1 = -L2E * Wih[2 * e + 1];
    const float wxz0 = -L2E * Wih[2 * (HH + e)],     wxz1 = -L2E * Wih[2 * (HH + e) + 1];
    const float wxn0 = -T2E * Wih[2 * (2 * HH + e)], wxn1 = -T2E * Wih[2 * (2 * HH + e) + 1];
    const float INVSs = -L2E * INVS;   // dequant+exp2 scale for r/z MFMA terms
    const float INVT2 = -T2E * INVS;   // dequant+exp2 scale for n MFMA term

    float hp = h0[(size_t)(b0 + batch) * HH + e];
    h8[0][batch][e] = (int8_t)(int)rintf(hp * 127.f);

    const int l0 = len[b0], l1 = len[b0 + 1];
    const int lm  = l0 > l1 ? l0 : l1;   // uniform loop bound
    const int lmy = batch ? l1 : l0;     // per-lane length
    const float2* xp = (const float2*)x + (size_t)(b0 + batch) * TT;
    float* op = out + (size_t)(b0 + batch) * HH + e;

    // A-frag: row m = lane&15 -> batch (m>>2)&1, 16-byte k chunk (lane>>4).
    const int8_t* abase = &h8[0][(lane >> 2) & 1][(lane >> 4) * 16];

    __syncthreads();

    float2 xv = xp[0];
    #pragma unroll 1
    for (int s = 0; s < lm; ++s) {
        const float2 xvn = xp[(s + 1) & (TT - 1)];   // prefetch next step's x

        // pre-scaled input-projection terms (independent of MFMA chain)
        const float gR = fmaf(xv.x, wxr0, fmaf(xv.y, wxr1, ccxs));
        const float gZ = fmaf(xv.x, wxz0, fmaf(xv.y, wxz1, ccys));
        const float gN = fmaf(xv.x, wxn0, fmaf(xv.y, wxn1, cczs));

        const int8_t* ap = abase + (s & 1) * (2 * HSTR8);  // h8 ping-pong
        v4i d0 = {0,0,0,0}, d1 = {0,0,0,0};
        v4i d4 = {0,0,0,0}, d5 = {0,0,0,0};
        v4i d2e = {0,0,0,0}, d2o = {0,0,0,0}, d3e = {0,0,0,0}, d3o = {0,0,0,0};

        // ---- phase A: R tiles (d0,d1) + N tiles (d4,d5), 16 MFMA ----
        // loads inline next to first use (R10 style); values reused in phase B
        const v4i a0 = *(const v4i*)(ap);
        d0 = __builtin_amdgcn_mfma_i32_16x16x64_i8(a0, wfr[0][0], d0, 0, 0, 0);
        d1 = __builtin_amdgcn_mfma_i32_16x16x64_i8(a0, wfr[1][0], d1, 0, 0, 0);
        d4 = __builtin_amdgcn_mfma_i32_16x16x64_i8(a0, wfr[4][0], d4, 0, 0, 0);
        d5 = __builtin_amdgcn_mfma_i32_16x16x64_i8(a0, wfr[5][0], d5, 0, 0, 0);
        const v4i a1 = *(const v4i*)(ap + 64);
        d0 = __builtin_amdgcn_mfma_i32_16x16x64_i8(a1, wfr[0][1], d0, 0, 0, 0);
        d1 = __builtin_amdgcn_mfma_i32_16x16x64_i8(a1, wfr[1][1], d1, 0, 0, 0);
        d4 = __builtin_amdgcn_mfma_i32_16x16x64_i8(a1, wfr[4][1], d4, 0, 0, 0);
        d5 = __builtin_amdgcn_mfma_i32_16x16x64_i8(a1, wfr[5][1], d5, 0, 0, 0);
        const v4i a2 = *(const v4i*)(ap + 128);
        d0 = __builtin_amdgcn_mfma_i32_16x16x64_i8(a2, wfr[0][2], d0, 0, 0, 0);
        d1 = __builtin_amdgcn_mfma_i32_16x16x64_i8(a2, wfr[1][2], d1, 0, 0, 0);
        d4 = __builtin_amdgcn_mfma_i32_16x16x64_i8(a2, wfr[4][2], d4, 0, 0, 0);
        d5 = __builtin_amdgcn_mfma_i32_16x16x64_i8(a2, wfr[5][2], d5, 0, 0, 0);
        const v4i a3 = *(const v4i*)(ap + 192);
        d0 = __builtin_amdgcn_mfma_i32_16x16x64_i8(a3, wfr[0][3], d0, 0, 0, 0);
        d1 = __builtin_amdgcn_mfma_i32_16x16x64_i8(a3, wfr[1][3], d1, 0, 0, 0);
        d4 = __builtin_amdgcn_mfma_i32_16x16x64_i8(a3, wfr[4][3], d4, 0, 0, 0);
        d5 = __builtin_amdgcn_mfma_i32_16x16x64_i8(a3, wfr[5][3], d5, 0, 0, 0);

        // long dependent chain r -> n, hidden under phase-B MFMA issue.
        // x' = -L2E*(uR*INVS + gR/ -L2E ...) : all scales pre-folded.
        const bool hi = lane >= 32;
        const float uRf = (float)(hi ? d1[0] : d0[0]);
        const float uNf = (float)(hi ? d5[0] : d4[0]);
        const float r = __builtin_amdgcn_rcpf(1.f + __builtin_exp2f(fmaf(uRf, INVSs, gR)));
        float yp = fmaf(r, fmaf(uNf, INVT2, ccw2), gN);     // -T2E * tanh-arg
        yp = fminf(fmaxf(yp, -43.3f), 43.3f);
        const float en = __builtin_exp2f(yp);
        const float n = (1.f - en) * __builtin_amdgcn_rcpf(1.f + en);
        const float hpn = hp - n;                            // tail prep

        // ---- phase B: Z tiles, 8 MFMA, A-frags reused from registers ----
        d2e = __builtin_amdgcn_mfma_i32_16x16x64_i8(a0, wfr[2][0], d2e, 0, 0, 0);
        d3e = __builtin_amdgcn_mfma_i32_16x16x64_i8(a0, wfr[3][0], d3e, 0, 0, 0);
        d2o = __builtin_amdgcn_mfma_i32_16x16x64_i8(a1, wfr[2][1], d2o, 0, 0, 0);
        d3o = __builtin_amdgcn_mfma_i32_16x16x64_i8(a1, wfr[3][1], d3o, 0, 0, 0);
        d2e = __builtin_amdgcn_mfma_i32_16x16x64_i8(a2, wfr[2][2], d2e, 0, 0, 0);
        d3e = __builtin_amdgcn_mfma_i32_16x16x64_i8(a2, wfr[3][2], d3e, 0, 0, 0);
        d2o = __builtin_amdgcn_mfma_i32_16x16x64_i8(a3, wfr[2][3], d2o, 0, 0, 0);
        d3o = __builtin_amdgcn_mfma_i32_16x16x64_i8(a3, wfr[3][3], d3o, 0, 0, 0);

        // true tail: z -> hn -> quant -> write
        const float uZf = (float)(hi ? (d3e[0] + d3o[0]) : (d2e[0] + d2o[0]));
        const float z = __builtin_amdgcn_rcpf(1.f + __builtin_exp2f(fmaf(uZf, INVSs, gZ)));
        float hn = fmaf(z, hpn, n);
        hn = (s < lmy) ? hn : hp;            // freeze finished batch
        h8[(s & 1) ^ 1][batch][e] = (int8_t)(int)rintf(hn * 127.f);
        hp = hn;
        xv = xvn;
        __syncthreads();   // new h8 buffer visible for next step's A reads
    }

    *op = hp;   // hs[len-1] (freeze preserved it past lmy)
}

extern "C" void kernel_launch(void* const* d_in, const int* in_sizes, int n_in,
                              void* d_out, int out_size, void* d_ws, size_t ws_size,
                              hipStream_t stream) {
    const float* x    = (const float*)d_in[0];
    const int*   lenp = (const int*)d_in[1];
    const float* h0   = (const float*)d_in[2];
    const float* Wih  = (const float*)d_in[3];
    const float* Whh  = (const float*)d_in[4];
    const float* bih  = (const float*)d_in[5];
    const float* bhh  = (const float*)d_in[6];
    float* out = (float*)d_out;

    uint4* Wp = (uint4*)d_ws;   // 192 KB scratch

    prep_pack_i8<<<NCT * KTI * 64 / 256, 256, 0, stream>>>(Whh, Wp);
    gru_persist<<<BB / 2, 512, 0, stream>>>(x, lenp, h0, Wih, bih, bhh, Wp, out);
}

// Round 6
// 360.753 us; speedup vs baseline: 1.0065x; 1.0065x over previous
//
#include <hip/hip_runtime.h>
#include <stdint.h>

// GRU encoder B=512,T=512,H=256,IN=2 — R14: R12 structure + pure-algebra wins.
// R12 base (349/321 us): i8 MFMA K=64, 48 MFMA/SIMD/step ~980 cyc pipe floor,
// h quant scale 127, W scale 2032, gates f32, hp unquantized in reg.
// R11+R13 lesson (both regressed): do NOT hand-schedule — the compiler's
// interleave of pragma-kt-loops with inline ds_reads (and phase-B LDS
// re-reads) is locally optimal. R14 = R12's EXACT loop structure, plus only:
//  1. exp2-folded sigmoid/tanh: 1.4427/2.8854 exp scales and INVS dequant
//     folded into loop-invariant pre-scaled constants (-2 VALU on r-chain,
//     -2 on tanh, -2 on z-tail; all serial-critical-path, no schedule change).
//  2. Post-loop output store (freeze preserves hp = h[lmy-1]); removes the
//     per-step compare + predicated store.

typedef int   v4i   __attribute__((ext_vector_type(4)));

#define BB 512
#define TT 512
#define HH 256
#define NCT 48     // 768/16 col tiles
#define KTI 4      // 256/64 k tiles (i8)
#define HSTR8 320  // padded h8 byte stride per batch
#define WSCALE 2032.0f
#define INVS (1.0f/(2032.0f*127.0f))
#define L2E  1.44269504f       // log2(e)
#define T2E  2.88539008f       // 2*log2(e)

// Wp[(ct*KTI + kt)*64 + lane] = 16 bytes W_hh[16ct + (lane&15)][64kt + (lane>>4)*16 + j]
__global__ void prep_pack_i8(const float* __restrict__ Whh, uint4* __restrict__ Wp) {
    int n = blockIdx.x * blockDim.x + threadIdx.x;   // [0, 48*4*64 = 12288)
    int lane = n & 63;
    int kt = (n >> 6) & (KTI - 1);
    int ct = n >> 8;
    int row = 16 * ct + (lane & 15);
    int k0  = 64 * kt + (lane >> 4) * 16;
    const float* src = Whh + (size_t)row * HH + k0;
    uint dw[4];
    #pragma unroll
    for (int d = 0; d < 4; ++d) {
        uint acc = 0;
        #pragma unroll
        for (int j = 0; j < 4; ++j) {
            int q = (int)rintf(src[4 * d + j] * WSCALE);
            q = q < -127 ? -127 : (q > 127 ? 127 : q);
            acc |= ((uint)(q & 0xff)) << (8 * j);
        }
        dw[d] = acc;
    }
    Wp[n] = uint4{dw[0], dw[1], dw[2], dw[3]};
}

__global__ void __launch_bounds__(512, 1)
gru_persist(const float* __restrict__ x,        // [B,T,2]
            const int* __restrict__ len,        // [B]
            const float* __restrict__ h0,       // [B,H]
            const float* __restrict__ Wih,      // [768,2]
            const float* __restrict__ bih,      // [768]
            const float* __restrict__ bhh,      // [768]
            const uint4* __restrict__ Wp,       // i8-packed W_hh fragments
            float* __restrict__ out)            // [B,H]
{
    __shared__ __align__(16) int8_t h8[2][2][HSTR8];   // [buf][batch][e]

    const int tid  = threadIdx.x;
    const int lane = tid & 63;
    const int w    = tid >> 6;          // wave 0..7
    const int b0   = blockIdx.x * 2;

    // ---- W B-fragments for this wave's 6 tiles: 96 dwords in regs ----
    v4i wfr[6][KTI];
    {
        const int cts[6] = {2*w, 2*w+1, 16+2*w, 16+2*w+1, 32+2*w, 32+2*w+1};
        #pragma unroll
        for (int c = 0; c < 6; ++c)
            #pragma unroll
            for (int kt = 0; kt < KTI; ++kt)
                wfr[c][kt] = __builtin_bit_cast(v4i, Wp[(cts[c] * KTI + kt) * 64 + lane]);
    }
    #pragma unroll
    for (int c = 0; c < 6; ++c)
        #pragma unroll
        for (int kt = 0; kt < KTI; ++kt)
            asm volatile("" : "+v"(wfr[c][kt]));   // reg-resident, not remat

    // ---- gate-slot mapping: one slot per lane ----
    const int batch = (lane >> 4) & 1;
    const int e = 32 * w + (lane & 15) + ((lane >> 5) << 4);

    // ---- loop-invariant gate constants, PRE-SCALED for exp2 folding ----
    // sigmoid(x) = rcp(1 + exp2(s*x)) with s = -L2E pre-folded
    // tanh(y):  e2 = exp2(-T2E*y); tanh = (1-e2)/(1+e2)
    const float ccxs = -L2E * (bih[e] + bhh[e]);                 // r bias'
    const float ccys = -L2E * (bih[HH + e] + bhh[HH + e]);       // z bias'
    const float cczs = -T2E * bih[2 * HH + e];                   // n input bias'
    const float ccw2 = bhh[2 * HH + e];                          // n hidden bias (unscaled)
    const float wxr0 = -L2E * Wih[2 * e],            wxr1 = -L2E * Wih[2 * e + 1];
    const float wxz0 = -L2E * Wih[2 * (HH + e)],     wxz1 = -L2E * Wih[2 * (HH + e) + 1];
    const float wxn0 = -T2E * Wih[2 * (2 * HH + e)], wxn1 = -T2E * Wih[2 * (2 * HH + e) + 1];
    const float INVSs = -L2E * INVS;   // dequant+exp2 scale for r/z MFMA terms
    const float INVT2 = -T2E * INVS;   // dequant+exp2 scale for n MFMA term
    const float ccw2s = -T2E * INVS * 0.f + ccw2;  // kept simple below

    float hp = h0[(size_t)(b0 + batch) * HH + e];
    h8[0][batch][e] = (int8_t)(int)rintf(hp * 127.f);

    const int l0 = len[b0], l1 = len[b0 + 1];
    const int lm  = l0 > l1 ? l0 : l1;   // uniform loop bound
    const int lmy = batch ? l1 : l0;     // per-lane length
    const float2* xp = (const float2*)x + (size_t)(b0 + batch) * TT;
    float* op = out + (size_t)(b0 + batch) * HH + e;

    // A-frag: row m = lane&15 -> batch (m>>2)&1, 16-byte k chunk (lane>>4).
    const int8_t* abase = &h8[0][(lane >> 2) & 1][(lane >> 4) * 16];

    __syncthreads();

    float2 xv = xp[0];
    #pragma unroll 1
    for (int s = 0; s < lm; ++s) {
        const float2 xvn = xp[(s + 1) & (TT - 1)];   // prefetch next step's x

        // pre-scaled input-projection terms (independent of MFMA chain)
        const float gR = fmaf(xv.x, wxr0, fmaf(xv.y, wxr1, ccxs));
        const float gZ = fmaf(xv.x, wxz0, fmaf(xv.y, wxz1, ccys));
        const float gN = fmaf(xv.x, wxn0, fmaf(xv.y, wxn1, cczs));

        const int8_t* ap = abase + (s & 1) * (2 * HSTR8);  // h8 ping-pong
        v4i d0 = {0,0,0,0}, d1 = {0,0,0,0};
        v4i d4 = {0,0,0,0}, d5 = {0,0,0,0};
        v4i d2e = {0,0,0,0}, d2o = {0,0,0,0}, d3e = {0,0,0,0}, d3o = {0,0,0,0};

        // ---- phase A: R tiles (d0,d1) + N tiles (d4,d5), 16 MFMA ----
        #pragma unroll
        for (int kt = 0; kt < KTI; ++kt) {
            const v4i a = *(const v4i*)(ap + kt * 64);   // ds_read_b128 broadcast
            d0 = __builtin_amdgcn_mfma_i32_16x16x64_i8(a, wfr[0][kt], d0, 0, 0, 0);
            d1 = __builtin_amdgcn_mfma_i32_16x16x64_i8(a, wfr[1][kt], d1, 0, 0, 0);
            d4 = __builtin_amdgcn_mfma_i32_16x16x64_i8(a, wfr[4][kt], d4, 0, 0, 0);
            d5 = __builtin_amdgcn_mfma_i32_16x16x64_i8(a, wfr[5][kt], d5, 0, 0, 0);
        }

        // long dependent chain r -> n, hidden under phase-B MFMA issue.
        // All exp scales pre-folded into constants; dequant fused into fmaf.
        const bool hi = lane >= 32;
        const float uRf = (float)(hi ? d1[0] : d0[0]);
        const float uNf = (float)(hi ? d5[0] : d4[0]);
        const float r = __builtin_amdgcn_rcpf(1.f + __builtin_exp2f(fmaf(uRf, INVSs, gR)));
        // tanh arg (pre-scaled by -T2E): gN + (-T2E)*r*(uN*INVS + ccw2)
        float yp = fmaf(-T2E * r, fmaf(uNf, INVS, ccw2s), gN);
        yp = fminf(fmaxf(yp, -43.3f), 43.3f);
        const float en = __builtin_exp2f(yp);
        const float n = (1.f - en) * __builtin_amdgcn_rcpf(1.f + en);
        const float hpn = hp - n;                            // tail prep

        // ---- phase B: Z tiles, 8 MFMA in 4 chains (dep-gap 4) ----
        #pragma unroll
        for (int kt = 0; kt < KTI; kt += 2) {
            const v4i a0 = *(const v4i*)(ap + kt * 64);
            const v4i a1 = *(const v4i*)(ap + (kt + 1) * 64);
            d2e = __builtin_amdgcn_mfma_i32_16x16x64_i8(a0, wfr[2][kt],     d2e, 0, 0, 0);
            d3e = __builtin_amdgcn_mfma_i32_16x16x64_i8(a0, wfr[3][kt],     d3e, 0, 0, 0);
            d2o = __builtin_amdgcn_mfma_i32_16x16x64_i8(a1, wfr[2][kt + 1], d2o, 0, 0, 0);
            d3o = __builtin_amdgcn_mfma_i32_16x16x64_i8(a1, wfr[3][kt + 1], d3o, 0, 0, 0);
        }

        // true tail: z -> hn -> quant -> write
        const int uZi = hi ? (d3e[0] + d3o[0]) : (d2e[0] + d2o[0]);
        const float z = __builtin_amdgcn_rcpf(1.f + __builtin_exp2f(fmaf((float)uZi, INVSs, gZ)));
        float hn = fmaf(z, hpn, n);
        hn = (s < lmy) ? hn : hp;            // freeze finished batch
        h8[(s & 1) ^ 1][batch][e] = (int8_t)(int)rintf(hn * 127.f);
        hp = hn;
        xv = xvn;
        __syncthreads();   // new h8 buffer visible for next step's A reads
    }

    *op = hp;   // hs[len-1] (freeze preserved it past lmy)
}

extern "C" void kernel_launch(void* const* d_in, const int* in_sizes, int n_in,
                              void* d_out, int out_size, void* d_ws, size_t ws_size,
                              hipStream_t stream) {
    const float* x    = (const float*)d_in[0];
    const int*   lenp = (const int*)d_in[1];
    const float* h0   = (const float*)d_in[2];
    const float* Wih  = (const float*)d_in[3];
    const float* Whh  = (const float*)d_in[4];
    const float* bih  = (const float*)d_in[5];
    const float* bhh  = (const float*)d_in[6];
    float* out = (float*)d_out;

    uint4* Wp = (uint4*)d_ws;   // 192 KB scratch

    prep_pack_i8<<<NCT * KTI * 64 / 256, 256, 0, stream>>>(Whh, Wp);
    gru_persist<<<BB / 2, 512, 0, stream>>>(x, lenp, h0, Wih, bih, bhh, Wp, out);
}